// Round 1
// 549.425 us; speedup vs baseline: 1.0038x; 1.0038x over previous
//
#include <hip/hip_runtime.h>

#define ND 100000
#define DD 128
#define HH 256
#define EE 640000
#define LL 5

// LDS view strides (in elements). 152/280 shorts = 76/140 words == 12 mod 32
// -> bank-group rotation 3 (coprime 8): even ds_read_b128 bank distribution.
#define GS 152   // gather view stride (shorts), 32 rows
#define ZS 280   // z view stride (shorts), 32 rows x 256 cols
#define OS 136   // out-stage bf16 stride (shorts)
#define OF 132   // out-stage fp32 stride (floats)

typedef __attribute__((ext_vector_type(8))) short short8;
typedef __attribute__((ext_vector_type(4))) short short4v;
typedef __attribute__((ext_vector_type(4))) float f32x4;

static __device__ __forceinline__ short f2bf(float f) {
    unsigned u = __builtin_bit_cast(unsigned, f);
    unsigned r = (u + 0x7fffu + ((u >> 16) & 1u)) >> 16;
    return (short)r;
}
static __device__ __forceinline__ float bf2f(short s) {
    unsigned u = ((unsigned)(unsigned short)s) << 16;
    return __builtin_bit_cast(float, u);
}

// ---------------------------------------------------------------------------
// setup: blocks [0,640) fold BN into weights (bf16 [n][k] pack);
//        blocks [640,13140) convert x fp32 -> bf16 into hbufA;
//        blocks [13140,15640) histogram dst degrees (cnt pre-zeroed).
// ---------------------------------------------------------------------------
__global__ __launch_bounds__(256) void setup(
    const float* __restrict__ W1, const float* __restrict__ b1,
    const float* __restrict__ g1, const float* __restrict__ bb1,
    const float* __restrict__ m1, const float* __restrict__ v1,
    const float* __restrict__ W2, const float* __restrict__ b2,
    const float* __restrict__ g2, const float* __restrict__ bb2,
    const float* __restrict__ m2, const float* __restrict__ v2,
    const float* __restrict__ x, const int* __restrict__ dst,
    short* __restrict__ W1p, float* __restrict__ b1e,
    short* __restrict__ W2p, float* __restrict__ b2e,
    short* __restrict__ hb, int* __restrict__ cnt)
{
    int bx = blockIdx.x;
    int tid = threadIdx.x;
    if (bx < 640) {
        int id = bx * 256 + tid;
        if (id < LL * HH * DD) {
            int l = id >> 15;
            int rem = id & 32767;
            {
                int n = rem >> 7, k = rem & 127;
                float s = g1[l * HH + n] * rsqrtf(v1[l * HH + n] + 1e-5f);
                W1p[id] = f2bf(W1[l * 32768 + k * HH + n] * s);
            }
            {
                int n2 = rem >> 8, k2 = rem & 255;
                float s = g2[l * DD + n2] * rsqrtf(v2[l * DD + n2] + 1e-5f);
                W2p[id] = f2bf(W2[l * 32768 + k2 * DD + n2] * s);
            }
        }
        if (id < LL * HH) {
            float s = g1[id] * rsqrtf(v1[id] + 1e-5f);
            b1e[id] = (b1[id] - m1[id]) * s + bb1[id];
        }
        if (id < LL * DD) {
            float s = g2[id] * rsqrtf(v2[id] + 1e-5f);
            b2e[id] = (b2[id] - m2[id]) * s + bb2[id];
        }
    } else if (bx < 13140) {
        int i = (bx - 640) * 256 + tid;          // ND*DD/4 = 3,200,000 float4s
        float4 v = reinterpret_cast<const float4*>(x)[i];
        short4v s;
        s.x = f2bf(v.x); s.y = f2bf(v.y); s.z = f2bf(v.z); s.w = f2bf(v.w);
        reinterpret_cast<short4v*>(hb)[i] = s;
    } else {
        int e = (bx - 13140) * 256 + tid;
        if (e < EE) atomicAdd(&cnt[dst[e]], 1);
    }
}

// per-block inclusive scan of cnt (in place) + block totals
__global__ __launch_bounds__(256) void scan_block(int* __restrict__ cnt, int* __restrict__ bsum)
{
    __shared__ int buf[256];
    int tid = threadIdx.x;
    int idx = blockIdx.x * 256 + tid;
    int v = (idx < ND) ? cnt[idx] : 0;
    buf[tid] = v;
    __syncthreads();
    int sum = v;
    for (int off = 1; off < 256; off <<= 1) {
        int t = (tid >= off) ? buf[tid - off] : 0;
        __syncthreads();
        sum += t;
        buf[tid] = sum;
        __syncthreads();
    }
    if (idx < ND) cnt[idx] = sum;
    if (tid == 255) bsum[blockIdx.x] = sum;
}

// merged: each block computes its exclusive prefix over bsum, then rowst
__global__ __launch_bounds__(256) void apply_offs2(const int* __restrict__ cnt,
                                                   const int* __restrict__ bsum,
                                                   int* __restrict__ rowst)
{
    __shared__ int sred[256];
    int tid = threadIdx.x;
    int partial = 0;
    for (int i = tid; i < blockIdx.x; i += 256) partial += bsum[i];
    sred[tid] = partial;
    __syncthreads();
    for (int off = 128; off > 0; off >>= 1) {
        if (tid < off) sred[tid] += sred[tid + off];
        __syncthreads();
    }
    int boff = sred[0];
    int idx = blockIdx.x * 256 + tid;
    if (idx < ND) rowst[idx + 1] = cnt[idx] + boff;
    if (idx == 0) rowst[0] = 0;
}

__global__ __launch_bounds__(256) void fill_csr(const int* __restrict__ src,
                                                const int* __restrict__ dst,
                                                const int* __restrict__ rowstart,
                                                int* __restrict__ cursor,
                                                int* __restrict__ csr)
{
    int e = blockIdx.x * 256 + threadIdx.x;
    if (e < EE) {
        int d = dst[e];
        int p = atomicAdd(&cursor[d], 1);
        csr[rowstart[d] + p] = src[e];
    }
}

// ---------------------------------------------------------------------------
// Fused GIN layer, 512 threads (8 waves) per 32-row block, 4 blocks/CU.
//   Stage A: gather, 2-deep software-pipelined 4-batches + batched 3-load tail
//            (no serial remainder loop; 4-8 independent 16B loads in flight).
//   GEMM1: wave owns 32 zcols x 32 nodes; W1 fragments pipelined in k-loop.
//   GEMM2: wave owns 16 outcols x 32 nodes; W2 fragments pipelined.
//   Stage E: LDS bounce -> fully coalesced 16B/lane global stores
//            (kills the 2x write amplification seen as WRITE_SIZE=50MB).
// LDS union: gather stride 152, z stride 280, out stride 136/132 (17,920 B).
// hb_in != hb_out (cross-block WAR hazard).
// ---------------------------------------------------------------------------
__global__ __launch_bounds__(512, 8) void layer_fused(
    const short* __restrict__ hb_in,
    const int* __restrict__ rowst,
    const int* __restrict__ csr,
    const short* __restrict__ W1l,    // [256][128] bf16
    const float* __restrict__ b1l,    // [256]
    const short* __restrict__ W2l,    // [128][256] bf16
    const float* __restrict__ b2l,    // [128]
    short* __restrict__ hb_out, float* __restrict__ f_out, int last)
{
    __shared__ __attribute__((aligned(16))) short sU[32 * ZS];   // 17,920 B

    const int tid = threadIdx.x;
    const int r0 = blockIdx.x * 32;          // 3125 * 32 = 100,000 exactly
    const int w = tid >> 6;
    const int lane = tid & 63;
    const int quad = lane >> 4;
    const int l16 = lane & 15;

    // ---- Stage A: neighbor gather, software-pipelined ----
    {
        const int row = tid >> 4;            // 0..31
        const int ch = (tid & 15) * 8;       // 0,8,...,120
        const int grow = r0 + row;
        const int s = rowst[grow], e = rowst[grow + 1];
        short8 h0 = *reinterpret_cast<const short8*>(&hb_in[(size_t)grow * DD + ch]);
        float acc[8];
        #pragma unroll
        for (int j = 0; j < 8; ++j) acc[j] = bf2f(h0[j]);

        const int deg = e - s;
        const int nfull = deg >> 2;
        const int rem = deg & 3;
        int i = s;
        short8 ca[4];
        if (nfull) {
            #pragma unroll
            for (int k = 0; k < 4; ++k)
                ca[k] = *reinterpret_cast<const short8*>(&hb_in[(size_t)csr[i + k] * DD + ch]);
            i += 4;
            for (int b = 1; b < nfull; ++b) {
                short8 na[4];
                #pragma unroll
                for (int k = 0; k < 4; ++k)
                    na[k] = *reinterpret_cast<const short8*>(&hb_in[(size_t)csr[i + k] * DD + ch]);
                i += 4;
                #pragma unroll
                for (int j = 0; j < 8; ++j)
                    acc[j] += (bf2f(ca[0][j]) + bf2f(ca[1][j])) + (bf2f(ca[2][j]) + bf2f(ca[3][j]));
                #pragma unroll
                for (int k = 0; k < 4; ++k) ca[k] = na[k];
            }
        }
        // tail loads issued before consuming the last full batch
        short8 t0, t1, t2;
        if (rem > 0) t0 = *reinterpret_cast<const short8*>(&hb_in[(size_t)csr[i] * DD + ch]);
        if (rem > 1) t1 = *reinterpret_cast<const short8*>(&hb_in[(size_t)csr[i + 1] * DD + ch]);
        if (rem > 2) t2 = *reinterpret_cast<const short8*>(&hb_in[(size_t)csr[i + 2] * DD + ch]);
        if (nfull) {
            #pragma unroll
            for (int j = 0; j < 8; ++j)
                acc[j] += (bf2f(ca[0][j]) + bf2f(ca[1][j])) + (bf2f(ca[2][j]) + bf2f(ca[3][j]));
        }
        if (rem > 0) {
            #pragma unroll
            for (int j = 0; j < 8; ++j) acc[j] += bf2f(t0[j]);
        }
        if (rem > 1) {
            #pragma unroll
            for (int j = 0; j < 8; ++j) acc[j] += bf2f(t1[j]);
        }
        if (rem > 2) {
            #pragma unroll
            for (int j = 0; j < 8; ++j) acc[j] += bf2f(t2[j]);
        }
        short8 o;
        #pragma unroll
        for (int j = 0; j < 8; ++j) o[j] = f2bf(acc[j]);
        *reinterpret_cast<short8*>(&sU[row * GS + ch]) = o;
    }
    __syncthreads();

    // ---- GEMM1' zT = W1(A) x agg(B): wave owns zcols [w*32, w*32+32) x 32 nodes ----
    const f32x4 zero4 = {0.f, 0.f, 0.f, 0.f};
    f32x4 acc1[2][2];
    #pragma unroll
    for (int h = 0; h < 2; ++h)
        #pragma unroll
        for (int nt = 0; nt < 2; ++nt) acc1[h][nt] = zero4;

    const int zr0 = w * 32 + l16;
    short8 a_cur0 = *reinterpret_cast<const short8*>(&W1l[zr0 * DD + quad * 8]);
    short8 a_cur1 = *reinterpret_cast<const short8*>(&W1l[(zr0 + 16) * DD + quad * 8]);

    __builtin_amdgcn_s_setprio(1);
    #pragma unroll
    for (int ks = 0; ks < 4; ++ks) {
        short8 a_n0, a_n1;
        if (ks < 3) {
            a_n0 = *reinterpret_cast<const short8*>(&W1l[zr0 * DD + (ks + 1) * 32 + quad * 8]);
            a_n1 = *reinterpret_cast<const short8*>(&W1l[(zr0 + 16) * DD + (ks + 1) * 32 + quad * 8]);
        }
        int kofs = ks * 32 + quad * 8;
        short8 b0 = *reinterpret_cast<const short8*>(&sU[l16 * GS + kofs]);
        short8 b1 = *reinterpret_cast<const short8*>(&sU[(16 + l16) * GS + kofs]);
        acc1[0][0] = __builtin_amdgcn_mfma_f32_16x16x32_bf16(a_cur0, b0, acc1[0][0], 0, 0, 0);
        acc1[0][1] = __builtin_amdgcn_mfma_f32_16x16x32_bf16(a_cur0, b1, acc1[0][1], 0, 0, 0);
        acc1[1][0] = __builtin_amdgcn_mfma_f32_16x16x32_bf16(a_cur1, b0, acc1[1][0], 0, 0, 0);
        acc1[1][1] = __builtin_amdgcn_mfma_f32_16x16x32_bf16(a_cur1, b1, acc1[1][1], 0, 0, 0);
        a_cur0 = a_n0; a_cur1 = a_n1;
    }
    __builtin_amdgcn_s_setprio(0);

    float4 bi0 = *reinterpret_cast<const float4*>(&b1l[w * 32 + quad * 4]);
    float4 bi1 = *reinterpret_cast<const float4*>(&b1l[w * 32 + 16 + quad * 4]);
    __syncthreads();   // gather view dead; z view reuses LDS

    // ---- Stage C: bias + ReLU -> sU[node][zcol] (stride ZS), 8B writes ----
    #pragma unroll
    for (int h = 0; h < 2; ++h) {
        float4 bi = h ? bi1 : bi0;
        int zc = w * 32 + h * 16 + quad * 4;
        #pragma unroll
        for (int nt = 0; nt < 2; ++nt) {
            int node = nt * 16 + l16;
            short4v o;
            o.x = f2bf(fmaxf(acc1[h][nt][0] + bi.x, 0.f));
            o.y = f2bf(fmaxf(acc1[h][nt][1] + bi.y, 0.f));
            o.z = f2bf(fmaxf(acc1[h][nt][2] + bi.z, 0.f));
            o.w = f2bf(fmaxf(acc1[h][nt][3] + bi.w, 0.f));
            *reinterpret_cast<short4v*>(&sU[node * ZS + zc]) = o;
        }
    }

    // Preload GEMM2 first weight fragment + bias while barrier settles
    const int orow = w * 16 + l16;
    short8 w_cur = *reinterpret_cast<const short8*>(&W2l[orow * HH + quad * 8]);
    float4 bi2 = *reinterpret_cast<const float4*>(&b2l[w * 16 + quad * 4]);
    __syncthreads();

    // ---- GEMM2' hT = W2(A) x z(B): wave owns outcols [w*16,+16) x 32 nodes ----
    f32x4 acc2[2];
    acc2[0] = zero4; acc2[1] = zero4;

    __builtin_amdgcn_s_setprio(1);
    #pragma unroll
    for (int ks = 0; ks < 8; ++ks) {
        short8 w_next;
        if (ks < 7)
            w_next = *reinterpret_cast<const short8*>(&W2l[orow * HH + (ks + 1) * 32 + quad * 8]);
        int kofs = ks * 32 + quad * 8;
        short8 b0 = *reinterpret_cast<const short8*>(&sU[l16 * ZS + kofs]);
        short8 b1 = *reinterpret_cast<const short8*>(&sU[(16 + l16) * ZS + kofs]);
        acc2[0] = __builtin_amdgcn_mfma_f32_16x16x32_bf16(w_cur, b0, acc2[0], 0, 0, 0);
        acc2[1] = __builtin_amdgcn_mfma_f32_16x16x32_bf16(w_cur, b1, acc2[1], 0, 0, 0);
        w_cur = w_next;
    }
    __builtin_amdgcn_s_setprio(0);
    __syncthreads();   // z view dead; out-stage view reuses LDS

    // ---- Stage E: bias (+ReLU) -> LDS bounce -> coalesced 16B/lane stores ----
    const int oc = w * 16 + quad * 4;
    if (!last) {
        #pragma unroll
        for (int nt = 0; nt < 2; ++nt) {
            int node = nt * 16 + l16;
            short4v o;
            o.x = f2bf(fmaxf(acc2[nt][0] + bi2.x, 0.f));
            o.y = f2bf(fmaxf(acc2[nt][1] + bi2.y, 0.f));
            o.z = f2bf(fmaxf(acc2[nt][2] + bi2.z, 0.f));
            o.w = f2bf(fmaxf(acc2[nt][3] + bi2.w, 0.f));
            *reinterpret_cast<short4v*>(&sU[node * OS + oc]) = o;
        }
        __syncthreads();
        int row = tid >> 4;
        int c8 = (tid & 15) * 8;
        short8 v = *reinterpret_cast<const short8*>(&sU[row * OS + c8]);
        *reinterpret_cast<short8*>(&hb_out[(size_t)(r0 + row) * DD + c8]) = v;
    } else {
        float* fU = reinterpret_cast<float*>(sU);
        #pragma unroll
        for (int nt = 0; nt < 2; ++nt) {
            int node = nt * 16 + l16;
            float4 o;
            o.x = acc2[nt][0] + bi2.x;
            o.y = acc2[nt][1] + bi2.y;
            o.z = acc2[nt][2] + bi2.z;
            o.w = acc2[nt][3] + bi2.w;
            *reinterpret_cast<float4*>(&fU[node * OF + oc]) = o;
        }
        __syncthreads();
        int row = tid >> 4;
        int cb = (tid & 15) * 8;
        float4 v0 = *reinterpret_cast<const float4*>(&fU[row * OF + cb]);
        float4 v1 = *reinterpret_cast<const float4*>(&fU[row * OF + cb + 4]);
        *reinterpret_cast<float4*>(&f_out[(size_t)(r0 + row) * DD + cb]) = v0;
        *reinterpret_cast<float4*>(&f_out[(size_t)(r0 + row) * DD + cb + 4]) = v1;
    }
}

extern "C" void kernel_launch(void* const* d_in, const int* in_sizes, int n_in,
                              void* d_out, int out_size, void* d_ws, size_t ws_size,
                              hipStream_t stream)
{
    const float* x  = (const float*)d_in[0];
    const int* ei   = (const int*)d_in[1];
    const int* src  = ei;
    const int* dst  = ei + EE;
    const float* W1 = (const float*)d_in[2];
    const float* b1 = (const float*)d_in[3];
    const float* g1 = (const float*)d_in[4];
    const float* bb1= (const float*)d_in[5];
    const float* m1 = (const float*)d_in[6];
    const float* v1 = (const float*)d_in[7];
    const float* W2 = (const float*)d_in[8];
    const float* b2 = (const float*)d_in[9];
    const float* g2 = (const float*)d_in[10];
    const float* bb2= (const float*)d_in[11];
    const float* m2 = (const float*)d_in[12];
    const float* v2 = (const float*)d_in[13];

    char* w = (char*)d_ws;
    short* hbufA = (short*)w;                                 // 25,600,000
    short* hbufB = (short*)(w + 25600000);                    // 25,600,000
    short* W1p   = (short*)(w + 51200000);                    //    327,680
    short* W2p   = (short*)(w + 51527680);                    //    327,680
    float* b1e   = (float*)(w + 51855360);                    //      5,120
    float* b2e   = (float*)(w + 51860480);                    //      2,560
    int*   cnt   = (int*)  (w + 51863040);                    //    400,000
    int*   cursor= (int*)  (w + 52263040);                    //    400,000 (contiguous after cnt)
    int*   rowst = (int*)  (w + 52663040);                    //    400,032
    int*   csr   = (int*)  (w + 53063072);                    //  2,560,000
    int*   bsum  = (int*)  (w + 55623072);                    //      1,664
    float* out   = (float*)d_out;

    // zero cnt + cursor (contiguous 800,000 B) — capture-safe async memset
    hipMemsetAsync(cnt, 0, 800000, stream);
    setup<<<15640, 256, 0, stream>>>(W1, b1, g1, bb1, m1, v1,
                                     W2, b2, g2, bb2, m2, v2,
                                     x, dst, W1p, b1e, W2p, b2e, hbufA, cnt);
    scan_block<<<391, 256, 0, stream>>>(cnt, bsum);
    apply_offs2<<<391, 256, 0, stream>>>(cnt, bsum, rowst);
    fill_csr<<<2500, 256, 0, stream>>>(src, dst, rowst, cursor, csr);

    short* hin = hbufA;
    short* hout = hbufB;
    for (int l = 0; l < LL; ++l) {
        layer_fused<<<3125, 512, 0, stream>>>(hin, rowst, csr,
                                              W1p + l * 32768, b1e + l * HH,
                                              W2p + l * 32768, b2e + l * DD,
                                              hout, out, (l == LL - 1) ? 1 : 0);
        short* t = hin; hin = hout; hout = t;
    }
}